// Round 5
// baseline (309.269 us; speedup 1.0000x reference)
//
#include <hip/hip_runtime.h>

#define NB 131072
#define NEG9 -1e9f

typedef __attribute__((ext_vector_type(8))) __bf16 bf16x8;
typedef __attribute__((ext_vector_type(4))) float f32x4;
typedef __attribute__((ext_vector_type(2))) unsigned int u32x2;
typedef __attribute__((ext_vector_type(4))) unsigned int u32x4;

__device__ __forceinline__ f32x4 mfma16(bf16x8 a, bf16x8 b, f32x4 c) {
    return __builtin_amdgcn_mfma_f32_16x16x32_bf16(a, b, c, 0, 0, 0);
}

// pack two floats to bf16x2 (truncation) in ONE v_perm_b32: [hi16(h) | hi16(l)]
__device__ __forceinline__ unsigned pk(float h, float l) {
    return __builtin_amdgcn_perm(__builtin_bit_cast(unsigned, h),
                                 __builtin_bit_cast(unsigned, l), 0x07060302u);
}
__device__ __forceinline__ unsigned pku(unsigned h, unsigned l) {
    return __builtin_amdgcn_perm(h, l, 0x07060302u);
}

// float -> bf16 (RNE) for weight prep
__device__ __forceinline__ unsigned short f2bf(float f) {
    unsigned u = __builtin_bit_cast(unsigned, f);
    u += 0x7fffu + ((u >> 16) & 1u);
    return (unsigned short)(u >> 16);
}

// BN-folded, transposed (n-major, k-contiguous) bf16 weights + fp32 biases.
struct __align__(16) Wspace {
    unsigned short W0t[512][64];
    unsigned short W1t[256][512];
    unsigned short nW1t[64][256];
    unsigned short dW1t[64][256];
    unsigned short nW2t[128][64];
    unsigned short dW2t[128][64];
    float c0[512];
    float c1[256];
    float nb1c[64], db1c[64];
    float nb2c[128], db2c[128];
};

__device__ Wspace g_ws;

__global__ void prep_kernel(
    const float* __restrict__ W0, const float* __restrict__ b0,
    const float* __restrict__ g0, const float* __restrict__ be0,
    const float* __restrict__ rm0, const float* __restrict__ rv0,
    const float* __restrict__ W1, const float* __restrict__ b1,
    const float* __restrict__ g1, const float* __restrict__ be1,
    const float* __restrict__ rm1, const float* __restrict__ rv1,
    const float* __restrict__ nW1, const float* __restrict__ nb1,
    const float* __restrict__ nW2, const float* __restrict__ nb2,
    const float* __restrict__ dW1, const float* __restrict__ db1,
    const float* __restrict__ dW2, const float* __restrict__ db2)
{
    const int tid = blockIdx.x * 256 + threadIdx.x;  // 0 .. 131071

    {   // W1t [256][512]: n = tid>>9, k = tid&511 (coalesced writes)
        int n = tid >> 9, k = tid & 511;
        float s = g1[n] * rsqrtf(rv1[n] + 1e-5f);
        ((unsigned short*)g_ws.W1t)[tid] = f2bf(W1[k * 256 + n] * s);
    }
    if (tid < 512 * 64) {  // W0t [512][64]
        int n = tid >> 6, k = tid & 63;
        float s = g0[n] * rsqrtf(rv0[n] + 1e-5f);
        ((unsigned short*)g_ws.W0t)[tid] = f2bf(W0[k * 512 + n] * s);
    }
    if (tid < 64 * 256) {  // nW1t/dW1t [64][256]
        int n = tid >> 8, k = tid & 255;
        ((unsigned short*)g_ws.nW1t)[tid] = f2bf(nW1[k * 64 + n]);
        ((unsigned short*)g_ws.dW1t)[tid] = f2bf(dW1[k * 64 + n]);
    }
    if (tid < 128 * 64) {  // nW2t/dW2t [128][64]
        int n = tid >> 6, k = tid & 63;
        ((unsigned short*)g_ws.nW2t)[tid] = f2bf(nW2[k * 128 + n]);
        ((unsigned short*)g_ws.dW2t)[tid] = f2bf(dW2[k * 128 + n]);
    }
    if (tid < 512) g_ws.c0[tid] = (b0[tid] - rm0[tid]) * (g0[tid] * rsqrtf(rv0[tid] + 1e-5f)) + be0[tid];
    if (tid < 256) g_ws.c1[tid] = (b1[tid] - rm1[tid]) * (g1[tid] * rsqrtf(rv1[tid] + 1e-5f)) + be1[tid];
    if (tid < 64) { g_ws.nb1c[tid] = nb1[tid]; g_ws.db1c[tid] = db1[tid]; }
    if (tid < 128) { g_ws.nb2c[tid] = nb2[tid]; g_ws.db2c[tid] = db2[tid]; }
}

// 1 block = 8 waves = 64 rows, bf16 (r2-r4 proven numerics/mask machinery).
// r5: An/Ad overlay into sReg -> LDS 40960 B.
// r6/r7 lesson: occupancy 44% vs 58% and VGPR 40/44/60 all ~identical perf
//   -> NOT latency/occupancy-bound; phase-local LDS read bursts are the
//   shared-resource suspect (~1.15 MB LDS reads/block, 8x wave redundancy).
// r8/r9: cut LDS reads ~40% using the registers r6 proved are free at (512,4):
//   (a) X hoisted to 32 VGPRs/wave (read once; layer0 256->64 KB/block)
//   (b) head1 re-split: 2 row-halves x 2 col-tiles/wave (256->128 KB)
//   (c) head2: a0/a1 hoisted over ct loop (128->64 KB)
//   (d) odd blocks run K-chunks 1,0 to de-correlate LDS bursts across blocks
//   (e) non-temporal output stores (131 MB streamed, keep L2 for weights)
//       [r9 fix: store ext-vector f32x4, not HIP float4 — builtin requires
//        a clang vector type]
//   Spill tripwire: FETCH/WRITE balloon vs 22/131 MB -> revert X-hoist.
__global__ __launch_bounds__(512, 4) void fused_mlp(
    const u32x4* __restrict__ xu, float* __restrict__ out)
{
    __shared__ __align__(16) unsigned short sXs [8 * 64 * 8];   //  8 KB (X, live to end)
    __shared__ __align__(16) unsigned short sReg[32 * 64 * 8];  // 32 KB (H0 chunk / H1 / An+Ad)

    const int tid = threadIdx.x;
    const int w = tid >> 6;          // wave 0..7
    const int lane = tid & 63;
    const int m = lane & 15;
    const int q = lane >> 4;
    const int qh = q >> 1;
    const int ql = (q & 1) * 4;
    const int row0 = blockIdx.x * 64;

    // ---- stage X -> bf16 granule-major [g][r][8] (one row-granule/thread) ----
    {
        int r = tid >> 3, g = tid & 7;
        u32x4 v0 = __builtin_nontemporal_load(&xu[(size_t)(row0 + r) * 16 + g * 2]);
        u32x4 v1 = __builtin_nontemporal_load(&xu[(size_t)(row0 + r) * 16 + g * 2 + 1]);
        u32x4 p = { pku(v0[1], v0[0]), pku(v0[3], v0[2]), pku(v1[1], v1[0]), pku(v1[3], v1[2]) };
        *(u32x4*)&sXs[(g * 64 + r) * 8] = p;
    }
    __syncthreads();

    // ---- hoist X fragments into registers: 8 x bf16x8 = 32 VGPR, read ONCE ----
    bf16x8 xr[2][4];
#pragma unroll
    for (int g2 = 0; g2 < 2; ++g2)
#pragma unroll
        for (int mt = 0; mt < 4; ++mt)
            xr[g2][mt] = *(const bf16x8*)&sXs[((g2 * 4 + q) * 64 + mt * 16 + m) * 8];

    // ---- layers 0+1, 2 K-chunks of 256; layer-1 partials in regs ----
    f32x4 acc1[2][4];
#pragma unroll
    for (int a = 0; a < 2; ++a)
#pragma unroll
        for (int b = 0; b < 4; ++b) acc1[a][b] = f32x4{0.f, 0.f, 0.f, 0.f};

    const int chsw = blockIdx.x & 1;   // phase stagger: odd blocks do ch 1,0
    for (int i = 0; i < 2; ++i) {
        const int ch = i ^ chsw;
        // layer0: wave w -> chunk cols [w*32,+32); X from regs (no LDS reads)
#pragma unroll
        for (int nt = 0; nt < 2; ++nt) {
            const int gcb = ch * 256 + w * 32 + nt * 16;
            bf16x8 wa0 = *(const bf16x8*)&g_ws.W0t[gcb + m][q * 8];
            bf16x8 wa1 = *(const bf16x8*)&g_ws.W0t[gcb + m][32 + q * 8];
            f32x4 bias = *(const f32x4*)&g_ws.c0[gcb + q * 4];
            const int kg = w * 4 + nt * 2 + qh;
#pragma unroll
            for (int mt = 0; mt < 4; ++mt) {
                f32x4 c = {0.f, 0.f, 0.f, 0.f};
                c = mfma16(wa0, xr[0][mt], c);
                c = mfma16(wa1, xr[1][mt], c);
                u32x2 pw = { pk(fmaxf(c[1] + bias[1], 0.f), fmaxf(c[0] + bias[0], 0.f)),
                             pk(fmaxf(c[3] + bias[3], 0.f), fmaxf(c[2] + bias[2], 0.f)) };
                *(u32x2*)&sReg[(kg * 64 + mt * 16 + m) * 8 + ql] = pw;
            }
        }
        __syncthreads();

        // layer1 partial: 8 independent accumulator tiles
#pragma unroll
        for (int ks = 0; ks < 8; ++ks) {
            bf16x8 wb[2], ab[4];
#pragma unroll
            for (int nt = 0; nt < 2; ++nt)
                wb[nt] = *(const bf16x8*)&g_ws.W1t[w * 32 + nt * 16 + m][ch * 256 + ks * 32 + q * 8];
#pragma unroll
            for (int mt = 0; mt < 4; ++mt)
                ab[mt] = *(const bf16x8*)&sReg[((ks * 4 + q) * 64 + mt * 16 + m) * 8];
#pragma unroll
            for (int nt = 0; nt < 2; ++nt)
#pragma unroll
                for (int mt = 0; mt < 4; ++mt)
                    acc1[nt][mt] = mfma16(wb[nt], ab[mt], acc1[nt][mt]);
        }
        __syncthreads();
    }

    // ---- H1 = relu(acc1 + c1) -> sReg (H0 region dead after last sync) ----
#pragma unroll
    for (int nt = 0; nt < 2; ++nt) {
        const int cb = w * 32 + nt * 16;
        f32x4 bias = *(const f32x4*)&g_ws.c1[cb + q * 4];
        const int kg = w * 4 + nt * 2 + qh;
#pragma unroll
        for (int mt = 0; mt < 4; ++mt) {
            f32x4 c = acc1[nt][mt];
            u32x2 pw = { pk(fmaxf(c[1] + bias[1], 0.f), fmaxf(c[0] + bias[0], 0.f)),
                         pk(fmaxf(c[3] + bias[3], 0.f), fmaxf(c[2] + bias[2], 0.f)) };
            *(u32x2*)&sReg[(kg * 64 + mt * 16 + m) * 8 + ql] = pw;
        }
    }
    __syncthreads();

    // ---- head layer 1: head = w>>2; per wave: 2 col-tiles x 2 row-halves ----
    // (halves each wave's H1 LDS reads vs 4-mt layout; weights L2-cached)
    const int head = w >> 2;
    {
        const int rh  = w & 1;           // row half: rows [rh*32, +32)
        const int ct2 = (w >> 1) & 1;    // col tile: cols [ct2*32, +32) within head
        const unsigned short (*Wh)[256] = head ? g_ws.dW1t : g_ws.nW1t;
        const float* bh = head ? g_ws.db1c : g_ws.nb1c;
        f32x4 acc[2][2];
#pragma unroll
        for (int a = 0; a < 2; ++a)
#pragma unroll
            for (int b = 0; b < 2; ++b) acc[a][b] = f32x4{0.f, 0.f, 0.f, 0.f};
#pragma unroll
        for (int ks = 0; ks < 8; ++ks) {
            bf16x8 wh[2], ab[2];
#pragma unroll
            for (int nt = 0; nt < 2; ++nt)
                wh[nt] = *(const bf16x8*)&Wh[ct2 * 32 + nt * 16 + m][ks * 32 + q * 8];
#pragma unroll
            for (int mt = 0; mt < 2; ++mt)
                ab[mt] = *(const bf16x8*)&sReg[((ks * 4 + q) * 64 + (rh * 2 + mt) * 16 + m) * 8];
#pragma unroll
            for (int nt = 0; nt < 2; ++nt)
#pragma unroll
                for (int mt = 0; mt < 2; ++mt)
                    acc[nt][mt] = mfma16(wh[nt], ab[mt], acc[nt][mt]);
        }
        // all waves' H1 reads must finish before A overlays sReg
        __syncthreads();
        unsigned short* Ah = sReg + (head ? 4096 : 0);  // An @ [0,8KB), Ad @ [8KB,16KB)
#pragma unroll
        for (int nt = 0; nt < 2; ++nt) {
            f32x4 bias = *(const f32x4*)&bh[ct2 * 32 + nt * 16 + q * 4];
            const int kg = ct2 * 4 + nt * 2 + qh;
#pragma unroll
            for (int mt = 0; mt < 2; ++mt) {
                f32x4 c = acc[nt][mt];
                u32x2 pw = { pk(fmaxf(c[1] + bias[1], 0.f), fmaxf(c[0] + bias[0], 0.f)),
                             pk(fmaxf(c[3] + bias[3], 0.f), fmaxf(c[2] + bias[2], 0.f)) };
                *(u32x2*)&Ah[(kg * 64 + (rh * 2 + mt) * 16 + m) * 8 + ql] = pw;
            }
        }
    }
    __syncthreads();

    // ---- head layer 2 + mask + non-temporal dwordx4 stores ----
    {
        const unsigned short (*W2)[64] = head ? g_ws.dW2t : g_ws.nW2t;
        const float* b2 = head ? g_ws.db2c : g_ws.nb2c;
        const unsigned short* Ah = sReg + (head ? 4096 : 0);
        float* op = out + (size_t)head * (size_t)NB * 128;

        // thresholds via r4's PROVEN sXs path: granule 7 elems 4,5 = cols 60,61
        // (class ids 0..127 exact in bf16); sXs untouched by the A overlay
        int thr[4];
#pragma unroll
        for (int mt = 0; mt < 4; ++mt) {
            unsigned tv = *(const unsigned*)&sXs[(7 * 64 + mt * 16 + m) * 8 + 4];
            thr[mt] = (int)__builtin_bit_cast(float, head ? (tv & 0xffff0000u) : (tv << 16));
        }
        // hoist both ct-tiles' weights/biases; a0/a1 read ONCE per mt (ct-invariant)
        bf16x8 w2f[2][2];
        f32x4 b2f[2];
#pragma unroll
        for (int ct = 0; ct < 2; ++ct) {
            const int ocb = (w & 3) * 32 + ct * 16;
            w2f[ct][0] = *(const bf16x8*)&W2[ocb + m][q * 8];
            w2f[ct][1] = *(const bf16x8*)&W2[ocb + m][32 + q * 8];
            b2f[ct] = *(const f32x4*)&b2[ocb + q * 4];
        }
#pragma unroll
        for (int mt = 0; mt < 4; ++mt) {
            bf16x8 a0 = *(const bf16x8*)&Ah[(q * 64 + mt * 16 + m) * 8];
            bf16x8 a1 = *(const bf16x8*)&Ah[((4 + q) * 64 + mt * 16 + m) * 8];
            const int t = thr[mt];
#pragma unroll
            for (int ct = 0; ct < 2; ++ct) {
                f32x4 c = {0.f, 0.f, 0.f, 0.f};
                c = mfma16(w2f[ct][0], a0, c);
                c = mfma16(w2f[ct][1], a1, c);
                const int ci = (w & 3) * 32 + ct * 16 + q * 4;
                f32x4 v;
                v[0] = (ci + 0 <= t) ? c[0] + b2f[ct][0] : NEG9;
                v[1] = (ci + 1 <= t) ? c[1] + b2f[ct][1] : NEG9;
                v[2] = (ci + 2 <= t) ? c[2] + b2f[ct][2] : NEG9;
                v[3] = (ci + 3 <= t) ? c[3] + b2f[ct][3] : NEG9;
                __builtin_nontemporal_store(v, (f32x4*)&op[(size_t)(row0 + mt * 16 + m) * 128 + ci]);
            }
        }
    }
}

extern "C" void kernel_launch(void* const* d_in, const int* in_sizes, int n_in,
                              void* d_out, int out_size, void* d_ws, size_t ws_size,
                              hipStream_t stream) {
    (void)in_sizes; (void)n_in; (void)d_ws; (void)ws_size;

    prep_kernel<<<512, 256, 0, stream>>>(
        (const float*)d_in[1], (const float*)d_in[2], (const float*)d_in[3],
        (const float*)d_in[4], (const float*)d_in[5], (const float*)d_in[6],
        (const float*)d_in[7], (const float*)d_in[8], (const float*)d_in[9],
        (const float*)d_in[10], (const float*)d_in[11], (const float*)d_in[12],
        (const float*)d_in[13], (const float*)d_in[14], (const float*)d_in[15],
        (const float*)d_in[16], (const float*)d_in[17], (const float*)d_in[18],
        (const float*)d_in[19], (const float*)d_in[20]);

    fused_mlp<<<NB / 64, 512, 0, stream>>>((const u32x4*)d_in[0], (float*)d_out);
}

// Round 6
// 288.040 us; speedup vs baseline: 1.0737x; 1.0737x over previous
//
#include <hip/hip_runtime.h>

#define NB 131072
#define NEG9 -1e9f

typedef __attribute__((ext_vector_type(8))) __bf16 bf16x8;
typedef __attribute__((ext_vector_type(4))) float f32x4;
typedef __attribute__((ext_vector_type(2))) unsigned int u32x2;
typedef __attribute__((ext_vector_type(4))) unsigned int u32x4;

__device__ __forceinline__ f32x4 mfma16(bf16x8 a, bf16x8 b, f32x4 c) {
    return __builtin_amdgcn_mfma_f32_16x16x32_bf16(a, b, c, 0, 0, 0);
}

// pack two floats to bf16x2 (truncation) in ONE v_perm_b32: [hi16(h) | hi16(l)]
__device__ __forceinline__ unsigned pk(float h, float l) {
    return __builtin_amdgcn_perm(__builtin_bit_cast(unsigned, h),
                                 __builtin_bit_cast(unsigned, l), 0x07060302u);
}
__device__ __forceinline__ unsigned pku(unsigned h, unsigned l) {
    return __builtin_amdgcn_perm(h, l, 0x07060302u);
}

// float -> bf16 (RNE) for weight prep
__device__ __forceinline__ unsigned short f2bf(float f) {
    unsigned u = __builtin_bit_cast(unsigned, f);
    u += 0x7fffu + ((u >> 16) & 1u);
    return (unsigned short)(u >> 16);
}

// BN-folded, transposed (n-major, k-contiguous) bf16 weights + fp32 biases.
struct __align__(16) Wspace {
    unsigned short W0t[512][64];
    unsigned short W1t[256][512];
    unsigned short nW1t[64][256];
    unsigned short dW1t[64][256];
    unsigned short nW2t[128][64];
    unsigned short dW2t[128][64];
    float c0[512];
    float c1[256];
    float nb1c[64], db1c[64];
    float nb2c[128], db2c[128];
};

__device__ Wspace g_ws;

__global__ void prep_kernel(
    const float* __restrict__ W0, const float* __restrict__ b0,
    const float* __restrict__ g0, const float* __restrict__ be0,
    const float* __restrict__ rm0, const float* __restrict__ rv0,
    const float* __restrict__ W1, const float* __restrict__ b1,
    const float* __restrict__ g1, const float* __restrict__ be1,
    const float* __restrict__ rm1, const float* __restrict__ rv1,
    const float* __restrict__ nW1, const float* __restrict__ nb1,
    const float* __restrict__ nW2, const float* __restrict__ nb2,
    const float* __restrict__ dW1, const float* __restrict__ db1,
    const float* __restrict__ dW2, const float* __restrict__ db2)
{
    const int tid = blockIdx.x * 256 + threadIdx.x;  // 0 .. 131071

    {   // W1t [256][512]: n = tid>>9, k = tid&511 (coalesced writes)
        int n = tid >> 9, k = tid & 511;
        float s = g1[n] * rsqrtf(rv1[n] + 1e-5f);
        ((unsigned short*)g_ws.W1t)[tid] = f2bf(W1[k * 256 + n] * s);
    }
    if (tid < 512 * 64) {  // W0t [512][64]
        int n = tid >> 6, k = tid & 63;
        float s = g0[n] * rsqrtf(rv0[n] + 1e-5f);
        ((unsigned short*)g_ws.W0t)[tid] = f2bf(W0[k * 512 + n] * s);
    }
    if (tid < 64 * 256) {  // nW1t/dW1t [64][256]
        int n = tid >> 8, k = tid & 255;
        ((unsigned short*)g_ws.nW1t)[tid] = f2bf(nW1[k * 64 + n]);
        ((unsigned short*)g_ws.dW1t)[tid] = f2bf(dW1[k * 64 + n]);
    }
    if (tid < 128 * 64) {  // nW2t/dW2t [128][64]
        int n = tid >> 6, k = tid & 63;
        ((unsigned short*)g_ws.nW2t)[tid] = f2bf(nW2[k * 128 + n]);
        ((unsigned short*)g_ws.dW2t)[tid] = f2bf(dW2[k * 128 + n]);
    }
    if (tid < 512) g_ws.c0[tid] = (b0[tid] - rm0[tid]) * (g0[tid] * rsqrtf(rv0[tid] + 1e-5f)) + be0[tid];
    if (tid < 256) g_ws.c1[tid] = (b1[tid] - rm1[tid]) * (g1[tid] * rsqrtf(rv1[tid] + 1e-5f)) + be1[tid];
    if (tid < 64) { g_ws.nb1c[tid] = nb1[tid]; g_ws.db1c[tid] = db1[tid]; }
    if (tid < 128) { g_ws.nb2c[tid] = nb2[tid]; g_ws.db2c[tid] = db2[tid]; }
}

// 1 block = 8 waves = 64 rows, bf16 (r2-r4 proven numerics/mask machinery).
// LEDGER: r5 spill (occupancy via reg-squeeze = -50%); r6 40KB LDS (neutral);
//   r7 3 blocks/CU (neutral->slight spill); r9 LDS-read cut -40% + nt stores
//   (nt stores +54MB HBM write amplification, regression; LDS cut neutral).
//   => occupancy, LDS footprint, LDS traffic all exonerated. All pipes ~15%.
//   SQ_LDS_BANK_CONFLICT is a stuck artifact (bit-identical across variants).
// r10 HYPOTHESIS: phase/barrier serialization. 8 full-block barriers, each a
//   full vmcnt(0)+lgkmcnt(0) drain, with thin phases that can't hide L2
//   weight-load latency; only 2 independent blocks/CU to overlap.
//   CHANGE: drop H0 K-chunking -> full 64x512 H0 in LDS (64KB). One fat L0
//   phase, one fat L1 phase (16 ks of pipelined load+MFMA), 6 barriers vs 8.
//   Keep X-reg-hoist; PLAIN stores (nt reverted); r6-proven head1/head2.
//   LDS 8+64=72KB -> 2 blocks/CU (proven cost-free).
__global__ __launch_bounds__(512, 4) void fused_mlp(
    const u32x4* __restrict__ xu, float* __restrict__ out)
{
    __shared__ __align__(16) unsigned short sXs[8 * 64 * 8];    //  8 KB (X, live to end)
    __shared__ __align__(16) unsigned short sH0[64 * 64 * 8];   // 64 KB (H0 full / H1 / An+Ad)

    const int tid = threadIdx.x;
    const int w = tid >> 6;          // wave 0..7
    const int lane = tid & 63;
    const int m = lane & 15;
    const int q = lane >> 4;
    const int qh = q >> 1;
    const int ql = (q & 1) * 4;
    const int row0 = blockIdx.x * 64;

    // ---- stage X -> bf16 granule-major [g][r][8] (one row-granule/thread) ----
    {
        int r = tid >> 3, g = tid & 7;
        u32x4 v0 = __builtin_nontemporal_load(&xu[(size_t)(row0 + r) * 16 + g * 2]);
        u32x4 v1 = __builtin_nontemporal_load(&xu[(size_t)(row0 + r) * 16 + g * 2 + 1]);
        u32x4 p = { pku(v0[1], v0[0]), pku(v0[3], v0[2]), pku(v1[1], v1[0]), pku(v1[3], v1[2]) };
        *(u32x4*)&sXs[(g * 64 + r) * 8] = p;
    }
    __syncthreads();   // B1

    // ---- hoist X fragments into registers: 8 x bf16x8 = 32 VGPR, read ONCE ----
    bf16x8 xr[2][4];
#pragma unroll
    for (int g2 = 0; g2 < 2; ++g2)
#pragma unroll
        for (int mt = 0; mt < 4; ++mt)
            xr[g2][mt] = *(const bf16x8*)&sXs[((g2 * 4 + q) * 64 + mt * 16 + m) * 8];

    // ---- layer0: FULL 512 cols in one phase; wave w -> cols [w*64, +64) ----
#pragma unroll
    for (int nt = 0; nt < 4; ++nt) {
        const int gcb = w * 64 + nt * 16;
        bf16x8 wa0 = *(const bf16x8*)&g_ws.W0t[gcb + m][q * 8];
        bf16x8 wa1 = *(const bf16x8*)&g_ws.W0t[gcb + m][32 + q * 8];
        f32x4 bias = *(const f32x4*)&g_ws.c0[gcb + q * 4];
        const int kg = w * 8 + nt * 2 + qh;    // granule 0..63
#pragma unroll
        for (int mt = 0; mt < 4; ++mt) {
            f32x4 c = {0.f, 0.f, 0.f, 0.f};
            c = mfma16(wa0, xr[0][mt], c);
            c = mfma16(wa1, xr[1][mt], c);
            u32x2 pw = { pk(fmaxf(c[1] + bias[1], 0.f), fmaxf(c[0] + bias[0], 0.f)),
                         pk(fmaxf(c[3] + bias[3], 0.f), fmaxf(c[2] + bias[2], 0.f)) };
            *(u32x2*)&sH0[(kg * 64 + mt * 16 + m) * 8 + ql] = pw;
        }
    }
    __syncthreads();   // B2

    // ---- layer1: K=512 in ONE phase, 16 ks of independent load+MFMA ----
    f32x4 acc1[2][4];
#pragma unroll
    for (int a = 0; a < 2; ++a)
#pragma unroll
        for (int b = 0; b < 4; ++b) acc1[a][b] = f32x4{0.f, 0.f, 0.f, 0.f};

#pragma unroll
    for (int ks = 0; ks < 16; ++ks) {
        bf16x8 wb[2], ab[4];
#pragma unroll
        for (int nt = 0; nt < 2; ++nt)
            wb[nt] = *(const bf16x8*)&g_ws.W1t[w * 32 + nt * 16 + m][ks * 32 + q * 8];
#pragma unroll
        for (int mt = 0; mt < 4; ++mt)
            ab[mt] = *(const bf16x8*)&sH0[((ks * 4 + q) * 64 + mt * 16 + m) * 8];
#pragma unroll
        for (int nt = 0; nt < 2; ++nt)
#pragma unroll
            for (int mt = 0; mt < 4; ++mt)
                acc1[nt][mt] = mfma16(wb[nt], ab[mt], acc1[nt][mt]);
    }
    __syncthreads();   // B3 (all H0 reads done; H1 may overlay)

    // ---- H1 = relu(acc1 + c1) -> sH0 granules [0,32) (H0 region dead) ----
#pragma unroll
    for (int nt = 0; nt < 2; ++nt) {
        const int cb = w * 32 + nt * 16;
        f32x4 bias = *(const f32x4*)&g_ws.c1[cb + q * 4];
        const int kg = w * 4 + nt * 2 + qh;    // granule 0..31
#pragma unroll
        for (int mt = 0; mt < 4; ++mt) {
            f32x4 c = acc1[nt][mt];
            u32x2 pw = { pk(fmaxf(c[1] + bias[1], 0.f), fmaxf(c[0] + bias[0], 0.f)),
                         pk(fmaxf(c[3] + bias[3], 0.f), fmaxf(c[2] + bias[2], 0.f)) };
            *(u32x2*)&sH0[(kg * 64 + mt * 16 + m) * 8 + ql] = pw;
        }
    }
    __syncthreads();   // B4

    // ---- head layer 1: head = w>>2, cols (w&3)*16..+16, K=256 ----
    const int head = w >> 2;
    {
        const int cb = (w & 3) * 16;
        const unsigned short (*Wh)[256] = head ? g_ws.dW1t : g_ws.nW1t;
        const float* bh = head ? g_ws.db1c : g_ws.nb1c;
        f32x4 acc[4];
#pragma unroll
        for (int b = 0; b < 4; ++b) acc[b] = f32x4{0.f, 0.f, 0.f, 0.f};
#pragma unroll
        for (int ks = 0; ks < 8; ++ks) {
            bf16x8 wh = *(const bf16x8*)&Wh[cb + m][ks * 32 + q * 8];
#pragma unroll
            for (int mt = 0; mt < 4; ++mt) {
                bf16x8 ab = *(const bf16x8*)&sH0[((ks * 4 + q) * 64 + mt * 16 + m) * 8];
                acc[mt] = mfma16(wh, ab, acc[mt]);
            }
        }
        __syncthreads();   // B5 (all H1 reads done; A may overlay)
        unsigned short* Ah = sH0 + (head ? 4096 : 0);  // An @ [0,8KB), Ad @ [8KB,16KB)
        f32x4 bias = *(const f32x4*)&bh[cb + q * 4];
        const int kg = (w & 3) * 2 + qh;
#pragma unroll
        for (int mt = 0; mt < 4; ++mt) {
            f32x4 c = acc[mt];
            u32x2 pw = { pk(fmaxf(c[1] + bias[1], 0.f), fmaxf(c[0] + bias[0], 0.f)),
                         pk(fmaxf(c[3] + bias[3], 0.f), fmaxf(c[2] + bias[2], 0.f)) };
            *(u32x2*)&Ah[(kg * 64 + mt * 16 + m) * 8 + ql] = pw;
        }
    }
    __syncthreads();   // B6

    // ---- head layer 2 + mask + plain dwordx4 stores ----
    {
        const unsigned short (*W2)[64] = head ? g_ws.dW2t : g_ws.nW2t;
        const float* b2 = head ? g_ws.db2c : g_ws.nb2c;
        const unsigned short* Ah = sH0 + (head ? 4096 : 0);
        float* op = out + (size_t)head * (size_t)NB * 128;

        // thresholds via r4's PROVEN sXs path: granule 7 elems 4,5 = cols 60,61
        // (class ids 0..127 exact in bf16); sXs untouched by the A overlay
        int thr[4];
#pragma unroll
        for (int mt = 0; mt < 4; ++mt) {
            unsigned tv = *(const unsigned*)&sXs[(7 * 64 + mt * 16 + m) * 8 + 4];
            thr[mt] = (int)__builtin_bit_cast(float, head ? (tv & 0xffff0000u) : (tv << 16));
        }
#pragma unroll
        for (int ct = 0; ct < 2; ++ct) {
            const int ocb = (w & 3) * 32 + ct * 16;
            bf16x8 w0 = *(const bf16x8*)&W2[ocb + m][q * 8];
            bf16x8 w1 = *(const bf16x8*)&W2[ocb + m][32 + q * 8];
            f32x4 bias = *(const f32x4*)&b2[ocb + q * 4];
#pragma unroll
            for (int mt = 0; mt < 4; ++mt) {
                bf16x8 a0 = *(const bf16x8*)&Ah[(q * 64 + mt * 16 + m) * 8];
                bf16x8 a1 = *(const bf16x8*)&Ah[((4 + q) * 64 + mt * 16 + m) * 8];
                f32x4 c = {0.f, 0.f, 0.f, 0.f};
                c = mfma16(w0, a0, c);
                c = mfma16(w1, a1, c);
                const int ci = ocb + q * 4;
                const int t = thr[mt];
                f32x4 v;
                v[0] = (ci + 0 <= t) ? c[0] + bias[0] : NEG9;
                v[1] = (ci + 1 <= t) ? c[1] + bias[1] : NEG9;
                v[2] = (ci + 2 <= t) ? c[2] + bias[2] : NEG9;
                v[3] = (ci + 3 <= t) ? c[3] + bias[3] : NEG9;
                *(f32x4*)&op[(size_t)(row0 + mt * 16 + m) * 128 + ci] = v;
            }
        }
    }
}

extern "C" void kernel_launch(void* const* d_in, const int* in_sizes, int n_in,
                              void* d_out, int out_size, void* d_ws, size_t ws_size,
                              hipStream_t stream) {
    (void)in_sizes; (void)n_in; (void)d_ws; (void)ws_size;

    prep_kernel<<<512, 256, 0, stream>>>(
        (const float*)d_in[1], (const float*)d_in[2], (const float*)d_in[3],
        (const float*)d_in[4], (const float*)d_in[5], (const float*)d_in[6],
        (const float*)d_in[7], (const float*)d_in[8], (const float*)d_in[9],
        (const float*)d_in[10], (const float*)d_in[11], (const float*)d_in[12],
        (const float*)d_in[13], (const float*)d_in[14], (const float*)d_in[15],
        (const float*)d_in[16], (const float*)d_in[17], (const float*)d_in[18],
        (const float*)d_in[19], (const float*)d_in[20]);

    fused_mlp<<<NB / 64, 512, 0, stream>>>((const u32x4*)d_in[0], (float*)d_out);
}

// Round 7
// 285.795 us; speedup vs baseline: 1.0821x; 1.0079x over previous
//
#include <hip/hip_runtime.h>

#define NB 131072
#define NEG9 -1e9f

typedef __attribute__((ext_vector_type(8))) __bf16 bf16x8;
typedef __attribute__((ext_vector_type(4))) float f32x4;
typedef __attribute__((ext_vector_type(2))) unsigned int u32x2;
typedef __attribute__((ext_vector_type(4))) unsigned int u32x4;

__device__ __forceinline__ f32x4 mfma16(bf16x8 a, bf16x8 b, f32x4 c) {
    return __builtin_amdgcn_mfma_f32_16x16x32_bf16(a, b, c, 0, 0, 0);
}

// pack two floats to bf16x2 (truncation) in ONE v_perm_b32: [hi16(h) | hi16(l)]
__device__ __forceinline__ unsigned pk(float h, float l) {
    return __builtin_amdgcn_perm(__builtin_bit_cast(unsigned, h),
                                 __builtin_bit_cast(unsigned, l), 0x07060302u);
}
__device__ __forceinline__ unsigned pku(unsigned h, unsigned l) {
    return __builtin_amdgcn_perm(h, l, 0x07060302u);
}

// float -> bf16 (RNE) for weight prep
__device__ __forceinline__ unsigned short f2bf(float f) {
    unsigned u = __builtin_bit_cast(unsigned, f);
    u += 0x7fffu + ((u >> 16) & 1u);
    return (unsigned short)(u >> 16);
}

// BN-folded, transposed (n-major, k-contiguous) bf16 weights + fp32 biases.
struct __align__(16) Wspace {
    unsigned short W0t[512][64];
    unsigned short W1t[256][512];
    unsigned short nW1t[64][256];
    unsigned short dW1t[64][256];
    unsigned short nW2t[128][64];
    unsigned short dW2t[128][64];
    float c0[512];
    float c1[256];
    float nb1c[64], db1c[64];
    float nb2c[128], db2c[128];
};

__device__ Wspace g_ws;

// r11: prep REWRITTEN. Old prep read W1[k*256+n] with k lane-fast = 1KB-stride
//   lane reads (64 lines/wave, 16x amplification, 1 load/thread, 8 waves/CU).
//   Bench-minus-fused residual was stable ~153-165us across r4-r10 => prep
//   was ~150us, BIGGER than fused. New prep: 53 blocks x 256 thr; one 64x64
//   tile per block, LDS transpose; float4-coalesced reads (BN-fold at read),
//   u32x2-coalesced bf16 writes. Block 52 does bias vectors.
__global__ __launch_bounds__(256) void prep_kernel(
    const float* __restrict__ W0, const float* __restrict__ b0,
    const float* __restrict__ g0, const float* __restrict__ be0,
    const float* __restrict__ rm0, const float* __restrict__ rv0,
    const float* __restrict__ W1, const float* __restrict__ b1,
    const float* __restrict__ g1, const float* __restrict__ be1,
    const float* __restrict__ rm1, const float* __restrict__ rv1,
    const float* __restrict__ nW1, const float* __restrict__ nb1,
    const float* __restrict__ nW2, const float* __restrict__ nb2,
    const float* __restrict__ dW1, const float* __restrict__ db1,
    const float* __restrict__ dW2, const float* __restrict__ db2)
{
    const int b = blockIdx.x;
    const int t = threadIdx.x;

    if (b == 52) {  // bias / BN-constant vectors (all coalesced)
        {   // c0[512]
            int i = t;          g_ws.c0[i] = (b0[i] - rm0[i]) * (g0[i] * rsqrtf(rv0[i] + 1e-5f)) + be0[i];
            i = t + 256;        g_ws.c0[i] = (b0[i] - rm0[i]) * (g0[i] * rsqrtf(rv0[i] + 1e-5f)) + be0[i];
        }
        g_ws.c1[t] = (b1[t] - rm1[t]) * (g1[t] * rsqrtf(rv1[t] + 1e-5f)) + be1[t];
        if (t < 64)  { g_ws.nb1c[t] = nb1[t]; g_ws.db1c[t] = db1[t]; }
        if (t < 128) { g_ws.nb2c[t] = nb2[t]; g_ws.db2c[t] = db2[t]; }
        return;
    }

    // ---- tile descriptor: src [K][sld] fp32 -> dst [N][dld] bf16 (transposed,
    //      optionally BN-scaled by s[n] = g[n]*rsqrt(rv[n]+eps)) ----
    const float* src; unsigned short* dst;
    const float* gp = nullptr; const float* rvp = nullptr;
    int sld, dld, k0, n0;
    if (b < 32)      { src = W1;  dst = (unsigned short*)g_ws.W1t;  sld = 256; dld = 512;
                       k0 = (b >> 2) * 64; n0 = (b & 3) * 64; gp = g1; rvp = rv1; }
    else if (b < 40) { src = W0;  dst = (unsigned short*)g_ws.W0t;  sld = 512; dld = 64;
                       k0 = 0; n0 = (b - 32) * 64; gp = g0; rvp = rv0; }
    else if (b < 44) { src = nW1; dst = (unsigned short*)g_ws.nW1t; sld = 64;  dld = 256;
                       k0 = (b - 40) * 64; n0 = 0; }
    else if (b < 48) { src = dW1; dst = (unsigned short*)g_ws.dW1t; sld = 64;  dld = 256;
                       k0 = (b - 44) * 64; n0 = 0; }
    else if (b < 50) { src = nW2; dst = (unsigned short*)g_ws.nW2t; sld = 128; dld = 64;
                       k0 = 0; n0 = (b - 48) * 64; }
    else             { src = dW2; dst = (unsigned short*)g_ws.dW2t; sld = 128; dld = 64;
                       k0 = 0; n0 = (b - 50) * 64; }

    __shared__ unsigned short tile[64][66];   // pad 66: 132B rows, 2-way-max banks

    const int rr = t >> 4;            // 0..15
    const int cc = (t & 15) * 4;      // 0,4,..,60

    // read phase: rows coalesced (16 lanes x float4 = 256B per row)
#pragma unroll
    for (int g = 0; g < 4; ++g) {
        const int r = rr + g * 16;    // tile row (source k = k0+r)
        f32x4 v = *(const f32x4*)&src[(size_t)(k0 + r) * sld + n0 + cc];
        if (gp) {
            f32x4 gv = *(const f32x4*)&gp[n0 + cc];
            f32x4 rv = *(const f32x4*)&rvp[n0 + cc];
            v[0] *= gv[0] * rsqrtf(rv[0] + 1e-5f);
            v[1] *= gv[1] * rsqrtf(rv[1] + 1e-5f);
            v[2] *= gv[2] * rsqrtf(rv[2] + 1e-5f);
            v[3] *= gv[3] * rsqrtf(rv[3] + 1e-5f);
        }
        *(unsigned*)&tile[r][cc]     = (unsigned)f2bf(v[0]) | ((unsigned)f2bf(v[1]) << 16);
        *(unsigned*)&tile[r][cc + 2] = (unsigned)f2bf(v[2]) | ((unsigned)f2bf(v[3]) << 16);
    }
    __syncthreads();

    // write phase: transposed rows coalesced (16 lanes x 8B = 128B per row)
#pragma unroll
    for (int g = 0; g < 4; ++g) {
        const int n = rr + g * 16;    // tile col = output row (n0+n)
        unsigned o01 = (unsigned)tile[cc + 0][n] | ((unsigned)tile[cc + 1][n] << 16);
        unsigned o23 = (unsigned)tile[cc + 2][n] | ((unsigned)tile[cc + 3][n] << 16);
        u32x2 o = { o01, o23 };
        *(u32x2*)&dst[(size_t)(n0 + n) * dld + k0 + cc] = o;
    }
}

// 1 block = 8 waves = 64 rows, bf16 (r2-r4 proven numerics/mask machinery).
// LEDGER: r5 spill (occupancy via reg-squeeze = -50%); r6 40KB LDS (neutral);
//   r7 3 blocks/CU (neutral->slight spill); r9 LDS-read cut -40% + nt stores
//   (regression); r10 fat phases, 6 barriers (134.5us, small win).
//   Fused plateau ~135us robust vs occupancy/LDS/traffic/phases.
//   SQ_LDS_BANK_CONFLICT is a stuck artifact (bit-identical across variants).
// r11: fused UNCHANGED from r10; this round targets prep only.
__global__ __launch_bounds__(512, 4) void fused_mlp(
    const u32x4* __restrict__ xu, float* __restrict__ out)
{
    __shared__ __align__(16) unsigned short sXs[8 * 64 * 8];    //  8 KB (X, live to end)
    __shared__ __align__(16) unsigned short sH0[64 * 64 * 8];   // 64 KB (H0 full / H1 / An+Ad)

    const int tid = threadIdx.x;
    const int w = tid >> 6;          // wave 0..7
    const int lane = tid & 63;
    const int m = lane & 15;
    const int q = lane >> 4;
    const int qh = q >> 1;
    const int ql = (q & 1) * 4;
    const int row0 = blockIdx.x * 64;

    // ---- stage X -> bf16 granule-major [g][r][8] (one row-granule/thread) ----
    {
        int r = tid >> 3, g = tid & 7;
        u32x4 v0 = __builtin_nontemporal_load(&xu[(size_t)(row0 + r) * 16 + g * 2]);
        u32x4 v1 = __builtin_nontemporal_load(&xu[(size_t)(row0 + r) * 16 + g * 2 + 1]);
        u32x4 p = { pku(v0[1], v0[0]), pku(v0[3], v0[2]), pku(v1[1], v1[0]), pku(v1[3], v1[2]) };
        *(u32x4*)&sXs[(g * 64 + r) * 8] = p;
    }
    __syncthreads();   // B1

    // ---- hoist X fragments into registers: 8 x bf16x8 = 32 VGPR, read ONCE ----
    bf16x8 xr[2][4];
#pragma unroll
    for (int g2 = 0; g2 < 2; ++g2)
#pragma unroll
        for (int mt = 0; mt < 4; ++mt)
            xr[g2][mt] = *(const bf16x8*)&sXs[((g2 * 4 + q) * 64 + mt * 16 + m) * 8];

    // ---- layer0: FULL 512 cols in one phase; wave w -> cols [w*64, +64) ----
#pragma unroll
    for (int nt = 0; nt < 4; ++nt) {
        const int gcb = w * 64 + nt * 16;
        bf16x8 wa0 = *(const bf16x8*)&g_ws.W0t[gcb + m][q * 8];
        bf16x8 wa1 = *(const bf16x8*)&g_ws.W0t[gcb + m][32 + q * 8];
        f32x4 bias = *(const f32x4*)&g_ws.c0[gcb + q * 4];
        const int kg = w * 8 + nt * 2 + qh;    // granule 0..63
#pragma unroll
        for (int mt = 0; mt < 4; ++mt) {
            f32x4 c = {0.f, 0.f, 0.f, 0.f};
            c = mfma16(wa0, xr[0][mt], c);
            c = mfma16(wa1, xr[1][mt], c);
            u32x2 pw = { pk(fmaxf(c[1] + bias[1], 0.f), fmaxf(c[0] + bias[0], 0.f)),
                         pk(fmaxf(c[3] + bias[3], 0.f), fmaxf(c[2] + bias[2], 0.f)) };
            *(u32x2*)&sH0[(kg * 64 + mt * 16 + m) * 8 + ql] = pw;
        }
    }
    __syncthreads();   // B2

    // ---- layer1: K=512 in ONE phase, 16 ks of independent load+MFMA ----
    f32x4 acc1[2][4];
#pragma unroll
    for (int a = 0; a < 2; ++a)
#pragma unroll
        for (int b = 0; b < 4; ++b) acc1[a][b] = f32x4{0.f, 0.f, 0.f, 0.f};

#pragma unroll
    for (int ks = 0; ks < 16; ++ks) {
        bf16x8 wb[2], ab[4];
#pragma unroll
        for (int nt = 0; nt < 2; ++nt)
            wb[nt] = *(const bf16x8*)&g_ws.W1t[w * 32 + nt * 16 + m][ks * 32 + q * 8];
#pragma unroll
        for (int mt = 0; mt < 4; ++mt)
            ab[mt] = *(const bf16x8*)&sH0[((ks * 4 + q) * 64 + mt * 16 + m) * 8];
#pragma unroll
        for (int nt = 0; nt < 2; ++nt)
#pragma unroll
            for (int mt = 0; mt < 4; ++mt)
                acc1[nt][mt] = mfma16(wb[nt], ab[mt], acc1[nt][mt]);
    }
    __syncthreads();   // B3 (all H0 reads done; H1 may overlay)

    // ---- H1 = relu(acc1 + c1) -> sH0 granules [0,32) (H0 region dead) ----
#pragma unroll
    for (int nt = 0; nt < 2; ++nt) {
        const int cb = w * 32 + nt * 16;
        f32x4 bias = *(const f32x4*)&g_ws.c1[cb + q * 4];
        const int kg = w * 4 + nt * 2 + qh;    // granule 0..31
#pragma unroll
        for (int mt = 0; mt < 4; ++mt) {
            f32x4 c = acc1[nt][mt];
            u32x2 pw = { pk(fmaxf(c[1] + bias[1], 0.f), fmaxf(c[0] + bias[0], 0.f)),
                         pk(fmaxf(c[3] + bias[3], 0.f), fmaxf(c[2] + bias[2], 0.f)) };
            *(u32x2*)&sH0[(kg * 64 + mt * 16 + m) * 8 + ql] = pw;
        }
    }
    __syncthreads();   // B4

    // ---- head layer 1: head = w>>2, cols (w&3)*16..+16, K=256 ----
    const int head = w >> 2;
    {
        const int cb = (w & 3) * 16;
        const unsigned short (*Wh)[256] = head ? g_ws.dW1t : g_ws.nW1t;
        const float* bh = head ? g_ws.db1c : g_ws.nb1c;
        f32x4 acc[4];
#pragma unroll
        for (int b = 0; b < 4; ++b) acc[b] = f32x4{0.f, 0.f, 0.f, 0.f};
#pragma unroll
        for (int ks = 0; ks < 8; ++ks) {
            bf16x8 wh = *(const bf16x8*)&Wh[cb + m][ks * 32 + q * 8];
#pragma unroll
            for (int mt = 0; mt < 4; ++mt) {
                bf16x8 ab = *(const bf16x8*)&sH0[((ks * 4 + q) * 64 + mt * 16 + m) * 8];
                acc[mt] = mfma16(wh, ab, acc[mt]);
            }
        }
        __syncthreads();   // B5 (all H1 reads done; A may overlay)
        unsigned short* Ah = sH0 + (head ? 4096 : 0);  // An @ [0,8KB), Ad @ [8KB,16KB)
        f32x4 bias = *(const f32x4*)&bh[cb + q * 4];
        const int kg = (w & 3) * 2 + qh;
#pragma unroll
        for (int mt = 0; mt < 4; ++mt) {
            f32x4 c = acc[mt];
            u32x2 pw = { pk(fmaxf(c[1] + bias[1], 0.f), fmaxf(c[0] + bias[0], 0.f)),
                         pk(fmaxf(c[3] + bias[3], 0.f), fmaxf(c[2] + bias[2], 0.f)) };
            *(u32x2*)&Ah[(kg * 64 + mt * 16 + m) * 8 + ql] = pw;
        }
    }
    __syncthreads();   // B6

    // ---- head layer 2 + mask + plain dwordx4 stores ----
    {
        const unsigned short (*W2)[64] = head ? g_ws.dW2t : g_ws.nW2t;
        const float* b2 = head ? g_ws.db2c : g_ws.nb2c;
        const unsigned short* Ah = sH0 + (head ? 4096 : 0);
        float* op = out + (size_t)head * (size_t)NB * 128;

        // thresholds via r4's PROVEN sXs path: granule 7 elems 4,5 = cols 60,61
        // (class ids 0..127 exact in bf16); sXs untouched by the A overlay
        int thr[4];
#pragma unroll
        for (int mt = 0; mt < 4; ++mt) {
            unsigned tv = *(const unsigned*)&sXs[(7 * 64 + mt * 16 + m) * 8 + 4];
            thr[mt] = (int)__builtin_bit_cast(float, head ? (tv & 0xffff0000u) : (tv << 16));
        }
#pragma unroll
        for (int ct = 0; ct < 2; ++ct) {
            const int ocb = (w & 3) * 32 + ct * 16;
            bf16x8 w0 = *(const bf16x8*)&W2[ocb + m][q * 8];
            bf16x8 w1 = *(const bf16x8*)&W2[ocb + m][32 + q * 8];
            f32x4 bias = *(const f32x4*)&b2[ocb + q * 4];
#pragma unroll
            for (int mt = 0; mt < 4; ++mt) {
                bf16x8 a0 = *(const bf16x8*)&Ah[(q * 64 + mt * 16 + m) * 8];
                bf16x8 a1 = *(const bf16x8*)&Ah[((4 + q) * 64 + mt * 16 + m) * 8];
                f32x4 c = {0.f, 0.f, 0.f, 0.f};
                c = mfma16(w0, a0, c);
                c = mfma16(w1, a1, c);
                const int ci = ocb + q * 4;
                const int t = thr[mt];
                f32x4 v;
                v[0] = (ci + 0 <= t) ? c[0] + bias[0] : NEG9;
                v[1] = (ci + 1 <= t) ? c[1] + bias[1] : NEG9;
                v[2] = (ci + 2 <= t) ? c[2] + bias[2] : NEG9;
                v[3] = (ci + 3 <= t) ? c[3] + bias[3] : NEG9;
                *(f32x4*)&op[(size_t)(row0 + mt * 16 + m) * 128 + ci] = v;
            }
        }
    }
}

extern "C" void kernel_launch(void* const* d_in, const int* in_sizes, int n_in,
                              void* d_out, int out_size, void* d_ws, size_t ws_size,
                              hipStream_t stream) {
    (void)in_sizes; (void)n_in; (void)d_ws; (void)ws_size;

    prep_kernel<<<53, 256, 0, stream>>>(
        (const float*)d_in[1], (const float*)d_in[2], (const float*)d_in[3],
        (const float*)d_in[4], (const float*)d_in[5], (const float*)d_in[6],
        (const float*)d_in[7], (const float*)d_in[8], (const float*)d_in[9],
        (const float*)d_in[10], (const float*)d_in[11], (const float*)d_in[12],
        (const float*)d_in[13], (const float*)d_in[14], (const float*)d_in[15],
        (const float*)d_in[16], (const float*)d_in[17], (const float*)d_in[18],
        (const float*)d_in[19], (const float*)d_in[20]);

    fused_mlp<<<NB / 64, 512, 0, stream>>>((const u32x4*)d_in[0], (float*)d_out);
}